// Round 8
// baseline (41.910 us; speedup 1.0000x reference)
//
#include <hip/hip_runtime.h>
#include <math.h>

static constexpr int B_ = 32;
static constexpr int T_ = 512;
static constexpr int D_ = 1024;
static constexpr int NT_ = 32;            // t-chunks per sample
static constexpr int TCHUNK_ = T_ / NT_;  // 16 rows per chunk (compile-time)
static constexpr int GRID1_ = 1024;       // pass-1 blocks (4/CU)
static constexpr float EPS_ = 1e-12f;

__device__ __forceinline__ float sl1f(float x) {
    float a = fabsf(x);
    return a < 1.0f ? 0.5f * x * x : a - 0.5f;
}

// Full 256-thread block reduce; returns total broadcast to all threads.
__device__ __forceinline__ float blockReduce256(float v, float* lds) {
#pragma unroll
    for (int o = 32; o > 0; o >>= 1) v += __shfl_down(v, o, 64);
    int wid = threadIdx.x >> 6, lane = threadIdx.x & 63;
    if (lane == 0) lds[wid] = v;
    __syncthreads();
    float tot = lds[0] + lds[1] + lds[2] + lds[3];
    __syncthreads();
    return tot;
}

// Pass 1: flat balanced chunk list. Per-chunk sums are accumulated into
// [B,D] LLC-resident accumulators via native f32 atomics (device-scope ->
// coherent point; leaves L2 clean so the dispatch-end flush is cheap).
// Word-loss scalar: one atomicAdd per chunk into wsWord[b].
// Block 0 zeroes out[0] (kernel boundary orders it before pass 2's adds).
__global__ __launch_bounds__(256, 4) void pass1_kernel(
    const float* __restrict__ preds, const float* __restrict__ wtarg,
    const int* __restrict__ lens,
    float* __restrict__ wsSumP, float* __restrict__ wsSumT,
    float* __restrict__ wsWord, float* __restrict__ out)
{
    __shared__ float lds[4];
    __shared__ int sPrefix[B_ + 1];   // exclusive prefix of ceil(len/16); [B_]=total
    __shared__ int sLen[B_];

    const int tid = threadIdx.x;
    if (blockIdx.x == 0 && tid == 0) out[0] = 0.f;

    if (tid < 64) {
        int len_t = (tid < B_) ? lens[tid] : 0;
        int nc = (len_t + TCHUNK_ - 1) / TCHUNK_;
        int incl = nc;
#pragma unroll
        for (int o = 1; o < 64; o <<= 1) {
            int u = __shfl_up(incl, o, 64);
            if (tid >= o) incl += u;
        }
        if (tid < B_) { sPrefix[tid] = incl - nc; sLen[tid] = len_t; }
        if (tid == B_ - 1) sPrefix[B_] = incl;
    }
    __syncthreads();
    const int total = sPrefix[B_];

    for (int fi = blockIdx.x; fi < total; fi += GRID1_) {
        // binary search: largest b with sPrefix[b] <= fi (uniform across block)
        int lo = 0, hi = B_;
        while (hi - lo > 1) {
            int mid = (lo + hi) >> 1;
            if (sPrefix[mid] <= fi) lo = mid; else hi = mid;
        }
        const int b = lo;
        const int c = fi - sPrefix[lo];
        const int len = sLen[b];
        const int t0 = c * TCHUNK_;
        const int nrows = min(TCHUNK_, len - t0);

        const float4* pp = reinterpret_cast<const float4*>(preds)
                           + (size_t)(b * T_ + t0) * (D_ / 4) + tid;
        const float4* pw = reinterpret_cast<const float4*>(wtarg)
                           + (size_t)(b * T_ + t0) * (D_ / 4) + tid;

        float4 ps = make_float4(0.f, 0.f, 0.f, 0.f);
        float4 ts = make_float4(0.f, 0.f, 0.f, 0.f);
        float s = 0.f;

        if (nrows == TCHUNK_) {
#pragma unroll
            for (int tt = 0; tt < TCHUNK_; tt += 8) {
                float4 p[8], w[8];
#pragma unroll
                for (int j = 0; j < 8; ++j) p[j] = pp[(size_t)(tt + j) * (D_ / 4)];
#pragma unroll
                for (int j = 0; j < 8; ++j) w[j] = pw[(size_t)(tt + j) * (D_ / 4)];
#pragma unroll
                for (int j = 0; j < 8; ++j) {
                    ps.x += p[j].x; ps.y += p[j].y; ps.z += p[j].z; ps.w += p[j].w;
                    ts.x += w[j].x; ts.y += w[j].y; ts.z += w[j].z; ts.w += w[j].w;
                    s += sl1f(p[j].x - w[j].x) + sl1f(p[j].y - w[j].y)
                       + sl1f(p[j].z - w[j].z) + sl1f(p[j].w - w[j].w);
                }
            }
        } else {
            for (int t = 0; t < nrows; ++t) {
                float4 p = pp[(size_t)t * (D_ / 4)];
                float4 w = pw[(size_t)t * (D_ / 4)];
                ps.x += p.x; ps.y += p.y; ps.z += p.z; ps.w += p.w;
                ts.x += w.x; ts.y += w.y; ts.z += w.z; ts.w += w.w;
                s += sl1f(p.x - w.x) + sl1f(p.y - w.y) + sl1f(p.z - w.z) + sl1f(p.w - w.w);
            }
        }

        // accumulate into [B,D] sums: 8 native f32 atomics per thread
        float* dstP = wsSumP + (size_t)b * D_ + tid * 4;
        float* dstT = wsSumT + (size_t)b * D_ + tid * 4;
        unsafeAtomicAdd(dstP + 0, ps.x);
        unsafeAtomicAdd(dstP + 1, ps.y);
        unsafeAtomicAdd(dstP + 2, ps.z);
        unsafeAtomicAdd(dstP + 3, ps.w);
        unsafeAtomicAdd(dstT + 0, ts.x);
        unsafeAtomicAdd(dstT + 1, ts.y);
        unsafeAtomicAdd(dstT + 2, ts.z);
        unsafeAtomicAdd(dstT + 3, ts.w);

        float tot = blockReduce256(s, lds);
        if (tid == 0) atomicAdd(&wsWord[b], tot);
    }
}

// Pass 2: 32 blocks, one per sample. Reads the [B,D] sums (12 KB/block),
// computes all three loss terms for b, atomicAdd into out[0].
__global__ __launch_bounds__(256) void pass2_kernel(
    const float* __restrict__ img, const int* __restrict__ lens,
    const float* __restrict__ wsSumP, const float* __restrict__ wsSumT,
    const float* __restrict__ wsWord, float* __restrict__ out)
{
    __shared__ float lred[4];
    const int b = blockIdx.x, tid = threadIdx.x;
    const int len = lens[b];
    const float flen = (float)len;

    const float4* img4 = reinterpret_cast<const float4*>(img);
    float4 im = img4[(size_t)b * (D_ / 4) + tid];
    float ss = im.x * im.x + im.y * im.y + im.z * im.z + im.w * im.w;
    float sumsq = blockReduce256(ss, lred);
    float inv_norm = 1.0f / fmaxf(sqrtf(sumsq), EPS_);

    float4 sp = reinterpret_cast<const float4*>(wsSumP)[(size_t)b * (D_ / 4) + tid];
    float4 st = reinterpret_cast<const float4*>(wsSumT)[(size_t)b * (D_ / 4) + tid];

    const float pmx = sp.x / flen, pmy = sp.y / flen, pmz = sp.z / flen, pmw = sp.w / flen;
    const float tmx = st.x / flen, tmy = st.y / flen, tmz = st.z / flen, tmw = st.w / flen;

    float s = sl1f(pmx - tmx) + sl1f(pmy - tmy) + sl1f(pmz - tmz) + sl1f(pmw - tmw)
            + sl1f(pmx - im.x * inv_norm) + sl1f(pmy - im.y * inv_norm)
            + sl1f(pmz - im.z * inv_norm) + sl1f(pmw - im.w * inv_norm);
    float tot = blockReduce256(s, lred);

    if (tid == 0) {
        float per_b = tot / (float)D_ + wsWord[b] / (flen * (float)D_);
        atomicAdd(out, per_b * (1.0f / (float)B_));
    }
}

extern "C" void kernel_launch(void* const* d_in, const int* in_sizes, int n_in,
                              void* d_out, int out_size, void* d_ws, size_t ws_size,
                              hipStream_t stream) {
    const float* wtarg = (const float*)d_in[0];   // word_targets [B,T,D]
    const float* img   = (const float*)d_in[1];   // image_targets [B,D]
    const float* preds = (const float*)d_in[2];   // preds [B,T,D]
    const int*   lens  = (const int*)d_in[3];     // decode_lengths [B]
    float* out = (float*)d_out;

    float* wsSumP = (float*)d_ws;                      // B*D floats (128 KB)
    float* wsSumT = wsSumP + (size_t)B_ * D_;          // B*D floats (128 KB)
    float* wsWord = wsSumT + (size_t)B_ * D_;          // B floats

    const size_t zero_bytes = ((size_t)2 * B_ * D_ + B_) * sizeof(float);
    hipMemsetAsync(d_ws, 0, zero_bytes, stream);       // graph-capturable memset node

    pass1_kernel<<<GRID1_, 256, 0, stream>>>(preds, wtarg, lens,
                                             wsSumP, wsSumT, wsWord, out);
    pass2_kernel<<<B_, 256, 0, stream>>>(img, lens, wsSumP, wsSumT, wsWord, out);
}

// Round 9
// 28.665 us; speedup vs baseline: 1.4621x; 1.4621x over previous
//
#include <hip/hip_runtime.h>
#include <math.h>

static constexpr int B_ = 32;
static constexpr int T_ = 512;
static constexpr int D_ = 1024;
static constexpr int NCH_ = 4;            // super-chunks per sample
static constexpr int TCH_ = T_ / NCH_;    // 128 rows per super-chunk
static constexpr int NDQ_ = 4;            // D quarters (256 floats each)
static constexpr float EPS_ = 1e-12f;

__device__ __forceinline__ float sl1f(float x) {
    float a = fabsf(x);
    return a < 1.0f ? 0.5f * x * x : a - 0.5f;
}

// Full 256-thread block reduce; returns total broadcast to all threads.
__device__ __forceinline__ float blockReduce256(float v, float* lds) {
#pragma unroll
    for (int o = 32; o > 0; o >>= 1) v += __shfl_down(v, o, 64);
    int wid = threadIdx.x >> 6, lane = threadIdx.x & 63;
    if (lane == 0) lds[wid] = v;
    __syncthreads();
    float tot = lds[0] + lds[1] + lds[2] + lds[3];
    __syncthreads();
    return tot;
}

// Pass 1: grid (NCH_, B_, NDQ_), 256 threads. Block (c,b,q) covers rows
// [c*128, min(+128, len)) x 256-float D-quarter q. Thread (r4=tid>>6, j=tid&63)
// accumulates rows r4, r4+4, ... for float4 column j IN REGISTERS, one LDS
// combine at the end, plain 1KB store. Partials: 1 MB total (was 8.4 MB in R7
// -> kernel-boundary L2 writeback + p2 re-read were the hidden 11.5 us).
// R8 lesson: no element-granularity atomics (28 MB RMW traffic, 40 us).
__global__ __launch_bounds__(256, 2) void pass1_kernel(
    const float* __restrict__ preds, const float* __restrict__ wtarg,
    const int* __restrict__ lens,
    float* __restrict__ wsPred, float* __restrict__ wsTarg,
    float* __restrict__ wsSl1, float* __restrict__ out)
{
    __shared__ float4 redP[4][64];
    __shared__ float4 redT[4][64];
    __shared__ float lred[4];

    const int c = blockIdx.x, b = blockIdx.y, q = blockIdx.z;
    const int tid = threadIdx.x;
    if (c == 0 && b == 0 && q == 0 && tid == 0) out[0] = 0.f;   // zeroed every call

    const int len = lens[b];
    const int t0 = c * TCH_;
    if (t0 >= len) return;                  // whole-block exit (before any barrier)
    const int nrows = min(TCH_, len - t0);

    const int j = tid & 63;                 // float4 column within quarter
    const int r4 = tid >> 6;                // row subset 0..3

    const float4* pp = reinterpret_cast<const float4*>(preds)
                       + (size_t)(b * T_ + t0) * (D_ / 4) + q * 64 + j;
    const float4* pw = reinterpret_cast<const float4*>(wtarg)
                       + (size_t)(b * T_ + t0) * (D_ / 4) + q * 64 + j;

    float4 ps = make_float4(0.f, 0.f, 0.f, 0.f);
    float4 ts = make_float4(0.f, 0.f, 0.f, 0.f);
    float s = 0.f;

    if (nrows == TCH_) {
        // 32 rows/thread, 8-row register batches
#pragma unroll
        for (int tt = 0; tt < 4; ++tt) {
            float4 p[8], w[8];
#pragma unroll
            for (int jj = 0; jj < 8; ++jj)
                p[jj] = pp[(size_t)(r4 + 4 * (tt * 8 + jj)) * (D_ / 4)];
#pragma unroll
            for (int jj = 0; jj < 8; ++jj)
                w[jj] = pw[(size_t)(r4 + 4 * (tt * 8 + jj)) * (D_ / 4)];
#pragma unroll
            for (int jj = 0; jj < 8; ++jj) {
                ps.x += p[jj].x; ps.y += p[jj].y; ps.z += p[jj].z; ps.w += p[jj].w;
                ts.x += w[jj].x; ts.y += w[jj].y; ts.z += w[jj].z; ts.w += w[jj].w;
                s += sl1f(p[jj].x - w[jj].x) + sl1f(p[jj].y - w[jj].y)
                   + sl1f(p[jj].z - w[jj].z) + sl1f(p[jj].w - w[jj].w);
            }
        }
    } else {
        for (int r = r4; r < nrows; r += 4) {
            float4 p = pp[(size_t)r * (D_ / 4)];
            float4 w = pw[(size_t)r * (D_ / 4)];
            ps.x += p.x; ps.y += p.y; ps.z += p.z; ps.w += p.w;
            ts.x += w.x; ts.y += w.y; ts.z += w.z; ts.w += w.w;
            s += sl1f(p.x - w.x) + sl1f(p.y - w.y) + sl1f(p.z - w.z) + sl1f(p.w - w.w);
        }
    }

    // combine the 4 row-subsets in LDS, store 256-float partial (plain store)
    redP[r4][j] = ps;
    redT[r4][j] = ts;
    float tot = blockReduce256(s, lred);    // includes the needed __syncthreads
    if (tid < 64) {
        float4 a0 = redP[0][tid], a1 = redP[1][tid], a2 = redP[2][tid], a3 = redP[3][tid];
        float4 ap = make_float4(a0.x + a1.x + a2.x + a3.x, a0.y + a1.y + a2.y + a3.y,
                                a0.z + a1.z + a2.z + a3.z, a0.w + a1.w + a2.w + a3.w);
        float4 b0 = redT[0][tid], b1 = redT[1][tid], b2 = redT[2][tid], b3 = redT[3][tid];
        float4 at = make_float4(b0.x + b1.x + b2.x + b3.x, b0.y + b1.y + b2.y + b3.y,
                                b0.z + b1.z + b2.z + b3.z, b0.w + b1.w + b2.w + b3.w);
        const size_t off = ((size_t)(b * NCH_ + c)) * (D_ / 4) + q * 64 + tid;
        reinterpret_cast<float4*>(wsPred)[off] = ap;
        reinterpret_cast<float4*>(wsTarg)[off] = at;
    }
    if (tid == 0) wsSl1[(b * NCH_ + c) * NDQ_ + q] = tot;
}

// Pass 2: 32 blocks (one per sample), 256 threads. Reads <=32 KB of partials +
// the image row, computes all three loss terms, one atomicAdd into out[0].
__global__ __launch_bounds__(256) void pass2_kernel(
    const float* __restrict__ img, const int* __restrict__ lens,
    const float* __restrict__ wsPred, const float* __restrict__ wsTarg,
    const float* __restrict__ wsSl1, float* __restrict__ out)
{
    __shared__ float lred[4];
    const int b = blockIdx.x, tid = threadIdx.x;
    const int len = lens[b];
    const float flen = (float)len;
    const int nc = (len + TCH_ - 1) / TCH_;      // super-chunks actually written

    // image norm (full row, all 256 threads; tid indexes 256 float4 = D)
    const float4* img4 = reinterpret_cast<const float4*>(img);
    float4 im = img4[(size_t)b * (D_ / 4) + tid];
    float ss = im.x * im.x + im.y * im.y + im.z * im.z + im.w * im.w;
    float sumsq = blockReduce256(ss, lred);
    float inv_norm = 1.0f / fmaxf(sqrtf(sumsq), EPS_);

    // combine chunk partials for this b (skip never-written chunks: ws poisoned)
    float4 ps = make_float4(0.f, 0.f, 0.f, 0.f);
    float4 ts = make_float4(0.f, 0.f, 0.f, 0.f);
#pragma unroll
    for (int c = 0; c < NCH_; ++c) {
        if (c < nc) {
            const size_t off = ((size_t)(b * NCH_ + c)) * (D_ / 4) + tid;
            float4 p = reinterpret_cast<const float4*>(wsPred)[off];
            float4 w = reinterpret_cast<const float4*>(wsTarg)[off];
            ps.x += p.x; ps.y += p.y; ps.z += p.z; ps.w += p.w;
            ts.x += w.x; ts.y += w.y; ts.z += w.z; ts.w += w.w;
        }
    }

    const float pmx = ps.x / flen, pmy = ps.y / flen, pmz = ps.z / flen, pmw = ps.w / flen;
    const float tmx = ts.x / flen, tmy = ts.y / flen, tmz = ts.z / flen, tmw = ts.w / flen;

    float s = sl1f(pmx - tmx) + sl1f(pmy - tmy) + sl1f(pmz - tmz) + sl1f(pmw - tmw)
            + sl1f(pmx - im.x * inv_norm) + sl1f(pmy - im.y * inv_norm)
            + sl1f(pmz - im.z * inv_norm) + sl1f(pmw - im.w * inv_norm);
    float tot = blockReduce256(s, lred);          // sentence + image sums over D

    // word-loss scalars: entries (c,q), c<nc; lanes 0..15 of wave 0
    float wv = 0.f;
    if (tid < NCH_ * NDQ_) {
        int c = tid >> 2;
        if (c < nc) wv = wsSl1[(b * NCH_ + c) * NDQ_ + (tid & 3)];
    }
    if (tid < 64) {
#pragma unroll
        for (int o = 32; o > 0; o >>= 1) wv += __shfl_down(wv, o, 64);
    }

    if (tid == 0) {
        float per_b = tot / (float)D_ + wv / (flen * (float)D_);
        atomicAdd(out, per_b * (1.0f / (float)B_));
    }
}

extern "C" void kernel_launch(void* const* d_in, const int* in_sizes, int n_in,
                              void* d_out, int out_size, void* d_ws, size_t ws_size,
                              hipStream_t stream) {
    const float* wtarg = (const float*)d_in[0];   // word_targets [B,T,D]
    const float* img   = (const float*)d_in[1];   // image_targets [B,D]
    const float* preds = (const float*)d_in[2];   // preds [B,T,D]
    const int*   lens  = (const int*)d_in[3];     // decode_lengths [B]
    float* out = (float*)d_out;

    float* wsPred = (float*)d_ws;                          // B*NCH*D floats (512 KB)
    float* wsTarg = wsPred + (size_t)B_ * NCH_ * D_;       // 512 KB
    float* wsSl1  = wsTarg + (size_t)B_ * NCH_ * D_;       // B*NCH*NDQ floats

    pass1_kernel<<<dim3(NCH_, B_, NDQ_), 256, 0, stream>>>(
        preds, wtarg, lens, wsPred, wsTarg, wsSl1, out);
    pass2_kernel<<<B_, 256, 0, stream>>>(img, lens, wsPred, wsTarg, wsSl1, out);
}

// Round 10
// 25.911 us; speedup vs baseline: 1.6175x; 1.1063x over previous
//
#include <hip/hip_runtime.h>
#include <math.h>

static constexpr int B_ = 32;
static constexpr int T_ = 512;
static constexpr int D_ = 1024;
static constexpr int WROWS_ = 64;             // rows per unit (window)
static constexpr int SLICE4_ = 32;            // float4 per D-slice (128 floats)
static constexpr int NSL_ = (D_ / 4) / SLICE4_;  // 8 slices
static constexpr int GRID1_ = 1024;           // pass-1 blocks (4/CU)
static constexpr float EPS_ = 1e-12f;

__device__ __forceinline__ float sl1f(float x) {
    float a = fabsf(x);
    return a < 1.0f ? 0.5f * x * x : a - 0.5f;
}

// Full 256-thread block reduce; returns total broadcast to all threads.
__device__ __forceinline__ float blockReduce256(float v, float* lds) {
#pragma unroll
    for (int o = 32; o > 0; o >>= 1) v += __shfl_down(v, o, 64);
    int wid = threadIdx.x >> 6, lane = threadIdx.x & 63;
    if (lane == 0) lds[wid] = v;
    __syncthreads();
    float tot = lds[0] + lds[1] + lds[2] + lds[3];
    __syncthreads();
    return tot;
}

// Pass 1: 1024 blocks, 256 threads, flat-balanced over ~1150 units.
// Unit = (b, slice s, window w) = rows [w*64, min(+64,len)) x 128-float slice.
// Thread (r8=tid>>5, j=tid&31): 8 rows in registers, LDS-combine 8 row-subsets,
// ONE 512B store per tensor per unit -> ~1 MB partials total (R7: 8.4 MB; that
// volume was paid 3x: store + boundary writeback + p2 re-read).
// R8 lesson: no element-granularity atomics. R9 lesson: keep unit quantum small.
__global__ __launch_bounds__(256, 4) void pass1_kernel(
    const float* __restrict__ preds, const float* __restrict__ wtarg,
    const int* __restrict__ lens,
    float* __restrict__ wsPred, float* __restrict__ wsTarg,
    float* __restrict__ wsSl1, float* __restrict__ out)
{
    __shared__ float4 redP[8][SLICE4_];
    __shared__ float4 redT[8][SLICE4_];
    __shared__ float lred[4];
    __shared__ int sEx[B_ + 1];     // exclusive prefix of units/sample; [B_]=total
    __shared__ int sNwin[B_];
    __shared__ int sLen[B_];

    const int tid = threadIdx.x;
    if (blockIdx.x == 0 && tid == 0) out[0] = 0.f;   // re-zeroed every call

    if (tid < 64) {
        int len_t = (tid < B_) ? lens[tid] : 0;
        int nwin = (len_t + WROWS_ - 1) / WROWS_;
        int nu = nwin * NSL_;
        int incl = nu;
#pragma unroll
        for (int o = 1; o < 64; o <<= 1) {
            int u = __shfl_up(incl, o, 64);
            if (tid >= o) incl += u;
        }
        if (tid < B_) { sEx[tid] = incl - nu; sNwin[tid] = nwin; sLen[tid] = len_t; }
        if (tid == B_ - 1) sEx[B_] = incl;
    }
    __syncthreads();
    const int total = sEx[B_];

    const int j = tid & (SLICE4_ - 1);   // float4 column within slice
    const int r8 = tid >> 5;             // row subset 0..7

    for (int fu = blockIdx.x; fu < total; fu += GRID1_) {
        // largest b with sEx[b] <= fu (uniform across block)
        int lo = 0, hi = B_;
        while (hi - lo > 1) {
            int mid = (lo + hi) >> 1;
            if (sEx[mid] <= fu) lo = mid; else hi = mid;
        }
        const int b = lo;
        const int rem = fu - sEx[b];
        const int nwin = sNwin[b];
        const int s = rem / nwin;
        const int w = rem - s * nwin;
        const int len = sLen[b];
        const int t0 = w * WROWS_;
        const int nr = min(WROWS_, len - t0);

        const float4* pp = reinterpret_cast<const float4*>(preds)
                           + (size_t)(b * T_ + t0) * (D_ / 4) + s * SLICE4_ + j;
        const float4* pw = reinterpret_cast<const float4*>(wtarg)
                           + (size_t)(b * T_ + t0) * (D_ / 4) + s * SLICE4_ + j;

        float4 ps = make_float4(0.f, 0.f, 0.f, 0.f);
        float4 ts = make_float4(0.f, 0.f, 0.f, 0.f);
        float sl = 0.f;

        if (nr == WROWS_) {
            float4 p[8], wv[8];
#pragma unroll
            for (int k = 0; k < 8; ++k) p[k] = pp[(size_t)(r8 + 8 * k) * (D_ / 4)];
#pragma unroll
            for (int k = 0; k < 8; ++k) wv[k] = pw[(size_t)(r8 + 8 * k) * (D_ / 4)];
#pragma unroll
            for (int k = 0; k < 8; ++k) {
                ps.x += p[k].x; ps.y += p[k].y; ps.z += p[k].z; ps.w += p[k].w;
                ts.x += wv[k].x; ts.y += wv[k].y; ts.z += wv[k].z; ts.w += wv[k].w;
                sl += sl1f(p[k].x - wv[k].x) + sl1f(p[k].y - wv[k].y)
                    + sl1f(p[k].z - wv[k].z) + sl1f(p[k].w - wv[k].w);
            }
        } else {
            for (int k = 0; k < 8; ++k) {
                int r = r8 + 8 * k;
                if (r < nr) {
                    float4 p = pp[(size_t)r * (D_ / 4)];
                    float4 wv = pw[(size_t)r * (D_ / 4)];
                    ps.x += p.x; ps.y += p.y; ps.z += p.z; ps.w += p.w;
                    ts.x += wv.x; ts.y += wv.y; ts.z += wv.z; ts.w += wv.w;
                    sl += sl1f(p.x - wv.x) + sl1f(p.y - wv.y)
                        + sl1f(p.z - wv.z) + sl1f(p.w - wv.w);
                }
            }
        }

        redP[r8][j] = ps;
        redT[r8][j] = ts;
        float tot = blockReduce256(sl, lred);   // syncthreads inside orders redP/redT

        if (tid < SLICE4_) {
            float4 ap = make_float4(0.f, 0.f, 0.f, 0.f);
            float4 at = make_float4(0.f, 0.f, 0.f, 0.f);
#pragma unroll
            for (int k = 0; k < 8; ++k) {
                float4 a = redP[k][tid], bb = redT[k][tid];
                ap.x += a.x; ap.y += a.y; ap.z += a.z; ap.w += a.w;
                at.x += bb.x; at.y += bb.y; at.z += bb.z; at.w += bb.w;
            }
            const size_t off = (size_t)fu * SLICE4_ + tid;
            reinterpret_cast<float4*>(wsPred)[off] = ap;
            reinterpret_cast<float4*>(wsTarg)[off] = at;
        }
        if (tid == 0) wsSl1[fu] = tot;
        __syncthreads();   // protect redP/redT before next iteration overwrites
    }
}

// Pass 2: 32 blocks (one per b), 256 threads = 8 slices x 32 cols = full D.
// Sums <=8 window-partials per thread (~1 MB total, cache-hot), image norm,
// all three loss terms, one atomicAdd into out[0] per block.
__global__ __launch_bounds__(256) void pass2_kernel(
    const float* __restrict__ img, const int* __restrict__ lens,
    const float* __restrict__ wsPred, const float* __restrict__ wsTarg,
    const float* __restrict__ wsSl1, float* __restrict__ out)
{
    __shared__ float lred[4];
    __shared__ int sEx[B_ + 1];
    __shared__ int sNwin[B_];

    const int b = blockIdx.x, tid = threadIdx.x;
    if (tid < 64) {
        int len_t = (tid < B_) ? lens[tid] : 0;
        int nwin = (len_t + WROWS_ - 1) / WROWS_;
        int nu = nwin * NSL_;
        int incl = nu;
#pragma unroll
        for (int o = 1; o < 64; o <<= 1) {
            int u = __shfl_up(incl, o, 64);
            if (tid >= o) incl += u;
        }
        if (tid < B_) { sEx[tid] = incl - nu; sNwin[tid] = nwin; }
        if (tid == B_ - 1) sEx[B_] = incl;
    }
    __syncthreads();

    const int base = sEx[b];
    const int nwin = sNwin[b];
    const int len = lens[b];
    const float flen = (float)len;
    const int s = tid >> 5, col = tid & 31;

    // combine window partials: units of (b,s) are contiguous at base + s*nwin
    float4 ps = make_float4(0.f, 0.f, 0.f, 0.f);
    float4 ts = make_float4(0.f, 0.f, 0.f, 0.f);
    for (int w = 0; w < nwin; ++w) {
        const size_t off = (size_t)(base + s * nwin + w) * SLICE4_ + col;
        float4 p = reinterpret_cast<const float4*>(wsPred)[off];
        float4 t = reinterpret_cast<const float4*>(wsTarg)[off];
        ps.x += p.x; ps.y += p.y; ps.z += p.z; ps.w += p.w;
        ts.x += t.x; ts.y += t.y; ts.z += t.z; ts.w += t.w;
    }

    // image norm: thread tid holds float4 index s*32+col == tid -> full row
    const float4* img4 = reinterpret_cast<const float4*>(img);
    float4 im = img4[(size_t)b * (D_ / 4) + tid];
    float ss = im.x * im.x + im.y * im.y + im.z * im.z + im.w * im.w;
    float sumsq = blockReduce256(ss, lred);
    float inv_norm = 1.0f / fmaxf(sqrtf(sumsq), EPS_);

    const float pmx = ps.x / flen, pmy = ps.y / flen, pmz = ps.z / flen, pmw = ps.w / flen;
    const float tmx = ts.x / flen, tmy = ts.y / flen, tmz = ts.z / flen, tmw = ts.w / flen;

    float sv = sl1f(pmx - tmx) + sl1f(pmy - tmy) + sl1f(pmz - tmz) + sl1f(pmw - tmw)
             + sl1f(pmx - im.x * inv_norm) + sl1f(pmy - im.y * inv_norm)
             + sl1f(pmz - im.z * inv_norm) + sl1f(pmw - im.w * inv_norm);
    float tot = blockReduce256(sv, lred);      // sentence + image sums over D

    // word-loss unit scalars: units of b are contiguous [base, base+nwin*8), <=64
    float wv = (tid < nwin * NSL_) ? wsSl1[base + tid] : 0.f;
    if (tid < 64) {
#pragma unroll
        for (int o = 32; o > 0; o >>= 1) wv += __shfl_down(wv, o, 64);
    }

    if (tid == 0) {
        float per_b = tot / (float)D_ + wv / (flen * (float)D_);
        atomicAdd(out, per_b * (1.0f / (float)B_));
    }
}

extern "C" void kernel_launch(void* const* d_in, const int* in_sizes, int n_in,
                              void* d_out, int out_size, void* d_ws, size_t ws_size,
                              hipStream_t stream) {
    const float* wtarg = (const float*)d_in[0];   // word_targets [B,T,D]
    const float* img   = (const float*)d_in[1];   // image_targets [B,D]
    const float* preds = (const float*)d_in[2];   // preds [B,T,D]
    const int*   lens  = (const int*)d_in[3];     // decode_lengths [B]
    float* out = (float*)d_out;

    // max units = B * ceil(T/64) * 8 = 2048
    float* wsPred = (float*)d_ws;                          // 2048*128 floats (1 MB)
    float* wsTarg = wsPred + (size_t)2048 * 128;           // 1 MB
    float* wsSl1  = wsTarg + (size_t)2048 * 128;           // 2048 floats

    pass1_kernel<<<GRID1_, 256, 0, stream>>>(preds, wtarg, lens,
                                             wsPred, wsTarg, wsSl1, out);
    pass2_kernel<<<B_, 256, 0, stream>>>(img, lens, wsPred, wsTarg, wsSl1, out);
}